// Round 16
// baseline (543.355 us; speedup 1.0000x reference)
//
#include <hip/hip_runtime.h>
#include <hip/hip_bf16.h>
#include <cstdint>
#include <cstddef>

typedef __attribute__((ext_vector_type(4))) float f32x4;
typedef __attribute__((ext_vector_type(8))) short s16x8;
typedef __attribute__((ext_vector_type(4))) unsigned int u32x4;

#define E_ 400000
#define D_ 128
#define H_ 512
#define CAT_ 384
#define BM 64
#define NBLK 6250                       // 400000/64 exact, no tail
#define SCRATCH 65536                   // 2KB LN partial scratch (64 edges x 4 quarters x 8B)
#define LDS_TOTAL (65536 + 2048)        // 67584 -> 2 blocks/CU -> 32 waves/CU = 8/SIMD
// cat (64 x 384 bf16) staged INSIDE the h buffer rows (h dead until the
// post-GEMM1 silu stores, which come after a barrier).

__device__ __forceinline__ unsigned cvtpk(float lo, float hi) {
  unsigned r;
  asm("v_cvt_pk_bf16_f32 %0, %1, %2" : "=v"(r) : "v"(lo), "v"(hi));
  return r;
}
__device__ __forceinline__ float silu_f(float x) {
  return x * __builtin_amdgcn_rcpf(1.0f + __expf(-x));
}

// h row stride 1024B would be 32-way bank conflict; XOR spread fixes it.
#define HS(row, byteoff) (smem + (row) * 1024 + ((byteoff) ^ (((row) & 7) << 4)))

// Swapped-operand MFMA: A = W frag (out-cols), B = activation frag (edges).
// D: lane&15 = edge, (lane>>4)*4 + r = out-col.
// 16 waves, 32-col slices: acc[4][2] = 32 regs -> fits the 64-reg cap at
// 8 waves/SIMD (the whole point of this round: 2x TLP for latency hiding).
__global__ __launch_bounds__(1024, 8)
void edge_mlp_fused(const float* __restrict__ efeat,
                    const float* __restrict__ src_feat,
                    const float* __restrict__ dst_feat,
                    const int* __restrict__ src_idx,
                    const int* __restrict__ dst_idx,
                    const unsigned short* __restrict__ P1,   // packed: p*16384 + kc*4096 + n*8
                    const unsigned short* __restrict__ P2,
                    const unsigned short* __restrict__ P3,   // p*4096 + kc*1024 + n*8
                    const float* __restrict__ b1,
                    const float* __restrict__ b2,
                    const float* __restrict__ b3,
                    const float* __restrict__ gamma,
                    const float* __restrict__ beta,
                    float* __restrict__ out) {
  extern __shared__ char smem[];
  const int tid = threadIdx.x;
  const int lane = tid & 63;
  const int wave = tid >> 6;            // 0..15
  const int lr = lane & 15;
  const int kc = lane >> 4;             // 0..3
  const int g4 = kc * 4;
  const size_t e0 = (size_t)blockIdx.x * BM;
  const int rot = ((blockIdx.x >> 8) & 1) << 3;   // de-phase co-resident blocks

  // per-wave W fragment base pointers (frag = contiguous 16B; 32-col slice)
  const unsigned short* w1base = P1 + (size_t)kc * 4096 + wave * 256 + lr * 8;
  const unsigned short* w2base = P2 + (size_t)kc * 4096 + wave * 256 + lr * 8;

  // ========== phase 0: one-shot gather -> cat in h region ==========
  // 16 threads per edge row, 8 floats (32B) per source each.
  {
    const int row = tid >> 4, q = tid & 15;
    const size_t ee = e0 + row;
    const float* bases[3];
    bases[0] = efeat + ee * D_;
    bases[1] = src_feat + (size_t)src_idx[ee] * D_;
    bases[2] = dst_feat + (size_t)dst_idx[ee] * D_;
    #pragma unroll
    for (int s = 0; s < 3; ++s) {
      const float* sp = bases[s] + q * 8;
      const f32x4 v0 = *(const f32x4*)sp;
      const f32x4 v1 = *(const f32x4*)(sp + 4);
      u32x4 r_;
      r_.x = cvtpk(v0[0], v0[1]); r_.y = cvtpk(v0[2], v0[3]);
      r_.z = cvtpk(v1[0], v1[1]); r_.w = cvtpk(v1[2], v1[3]);
      *(u32x4*)HS(row, (s * 128 + q * 8) * 2) = r_;
    }
  }
  asm volatile("s_waitcnt lgkmcnt(0)" ::: "memory");
  __builtin_amdgcn_s_barrier();          // cat visible
  asm volatile("" ::: "memory");

  // ========== GEMM1: cat[64x384] @ W1 -> silu -> h1 ==========
  {
    f32x4 acc[4][2];
    #pragma unroll
    for (int eg = 0; eg < 4; ++eg)
      #pragma unroll
      for (int j = 0; j < 2; ++j) acc[eg][j] = (f32x4){0.f, 0.f, 0.f, 0.f};

    #pragma unroll 2
    for (int p = 0; p < 12; ++p) {
      s16x8 w[2];
      #pragma unroll
      for (int j = 0; j < 2; ++j)
        w[j] = *(const s16x8*)(w1base + (size_t)p * 16384 + j * 128);
      #pragma unroll
      for (int eg = 0; eg < 4; ++eg) {
        const s16x8 bf = *(const s16x8*)HS(eg * 16 + lr, p * 64 + kc * 16);
        #pragma unroll
        for (int j = 0; j < 2; ++j)
          acc[eg][j] = __builtin_amdgcn_mfma_f32_16x16x32_bf16(w[j], bf, acc[eg][j], 0, 0, 0);
      }
    }

    __builtin_amdgcn_s_barrier();        // all cat reads done before h1 overwrite
    asm volatile("" ::: "memory");

    #pragma unroll
    for (int j = 0; j < 2; ++j) {
      const int col0 = wave * 32 + j * 16 + g4;
      const f32x4 bv = *(const f32x4*)(b1 + col0);
      #pragma unroll
      for (int eg = 0; eg < 4; ++eg) {
        uint2 o_;
        o_.x = cvtpk(silu_f(acc[eg][j][0] + bv[0]), silu_f(acc[eg][j][1] + bv[1]));
        o_.y = cvtpk(silu_f(acc[eg][j][2] + bv[2]), silu_f(acc[eg][j][3] + bv[3]));
        *(uint2*)HS(eg * 16 + lr, col0 * 2) = o_;
      }
    }
  }
  asm volatile("s_waitcnt lgkmcnt(0)" ::: "memory");
  __builtin_amdgcn_s_barrier();          // h1 visible
  asm volatile("" ::: "memory");

  // ========== GEMM2: h1[64x512] @ W2 -> silu -> h2 (rotated K-loop) ==========
  {
    f32x4 acc[4][2];
    #pragma unroll
    for (int eg = 0; eg < 4; ++eg)
      #pragma unroll
      for (int j = 0; j < 2; ++j) acc[eg][j] = (f32x4){0.f, 0.f, 0.f, 0.f};

    #pragma unroll 2
    for (int pp = 0; pp < 16; ++pp) {
      const int p = (pp + rot) & 15;
      s16x8 w[2];
      #pragma unroll
      for (int j = 0; j < 2; ++j)
        w[j] = *(const s16x8*)(w2base + (size_t)p * 16384 + j * 128);
      #pragma unroll
      for (int eg = 0; eg < 4; ++eg) {
        const s16x8 bf = *(const s16x8*)HS(eg * 16 + lr, p * 64 + kc * 16);
        #pragma unroll
        for (int j = 0; j < 2; ++j)
          acc[eg][j] = __builtin_amdgcn_mfma_f32_16x16x32_bf16(w[j], bf, acc[eg][j], 0, 0, 0);
      }
    }

    __builtin_amdgcn_s_barrier();        // all h1 reads done before h2 overwrite
    asm volatile("" ::: "memory");

    #pragma unroll
    for (int j = 0; j < 2; ++j) {
      const int col0 = wave * 32 + j * 16 + g4;
      const f32x4 bv = *(const f32x4*)(b2 + col0);
      #pragma unroll
      for (int eg = 0; eg < 4; ++eg) {
        uint2 o_;
        o_.x = cvtpk(silu_f(acc[eg][j][0] + bv[0]), silu_f(acc[eg][j][1] + bv[1]));
        o_.y = cvtpk(silu_f(acc[eg][j][2] + bv[2]), silu_f(acc[eg][j][3] + bv[3]));
        *(uint2*)HS(eg * 16 + lr, col0 * 2) = o_;
      }
    }
  }
  asm volatile("s_waitcnt lgkmcnt(0)" ::: "memory");
  __builtin_amdgcn_s_barrier();          // h2 visible
  asm volatile("" ::: "memory");

  // ===== GEMM3: 16 waves = (edge-group 0..3) x (col-quarter 0..3) =====
  {
    const int q3 = wave & 3;             // 32-col quarter
    const int eg3 = wave >> 2;           // 16-edge group
    const int edge = eg3 * 16 + lr;

    f32x4 acc[2];
    #pragma unroll
    for (int j = 0; j < 2; ++j) acc[j] = (f32x4){0.f, 0.f, 0.f, 0.f};

    const unsigned short* w3b = P3 + (size_t)kc * 1024 + q3 * 256 + lr * 8;

    #pragma unroll 2
    for (int pp = 0; pp < 16; ++pp) {
      const int p = (pp + rot) & 15;
      s16x8 w[2];
      #pragma unroll
      for (int j = 0; j < 2; ++j)
        w[j] = *(const s16x8*)(w3b + (size_t)p * 4096 + j * 128);
      const s16x8 bf = *(const s16x8*)HS(edge, p * 64 + kc * 16);
      #pragma unroll
      for (int j = 0; j < 2; ++j)
        acc[j] = __builtin_amdgcn_mfma_f32_16x16x32_bf16(w[j], bf, acc[j], 0, 0, 0);
    }

    // bias + per-quarter partial sums
    float sum = 0.f, ss = 0.f;
    #pragma unroll
    for (int j = 0; j < 2; ++j) {
      const f32x4 bv = *(const f32x4*)(b3 + q3 * 32 + j * 16 + g4);
      #pragma unroll
      for (int r = 0; r < 4; ++r) {
        acc[j][r] += bv[r];
        sum += acc[j][r];
        ss += acc[j][r] * acc[j][r];
      }
    }
    sum += __shfl_xor(sum, 16, 64); ss += __shfl_xor(ss, 16, 64);
    sum += __shfl_xor(sum, 32, 64); ss += __shfl_xor(ss, 32, 64);

    if (lane < 16) {
      float2 pw; pw.x = sum; pw.y = ss;
      *(float2*)(smem + SCRATCH + edge * 32 + q3 * 8) = pw;
    }
    asm volatile("s_waitcnt lgkmcnt(0)" ::: "memory");
    __builtin_amdgcn_s_barrier();
    asm volatile("" ::: "memory");

    const f32x4 pa = *(const f32x4*)(smem + SCRATCH + edge * 32);
    const f32x4 pb = *(const f32x4*)(smem + SCRATCH + edge * 32 + 16);
    const float sumT = pa[0] + pa[2] + pb[0] + pb[2];
    const float ssT  = pa[1] + pa[3] + pb[1] + pb[3];
    const float mu = sumT * (1.0f / 128.0f);
    const float var = ssT * (1.0f / 128.0f) - mu * mu;
    const float rstd = rsqrtf(var + 1e-5f);

    float* orow = out + (e0 + edge) * D_ + q3 * 32;
    #pragma unroll
    for (int j = 0; j < 2; ++j) {
      const f32x4 gv  = *(const f32x4*)(gamma + q3 * 32 + j * 16 + g4);
      const f32x4 btv = *(const f32x4*)(beta  + q3 * 32 + j * 16 + g4);
      f32x4 o;
      #pragma unroll
      for (int r = 0; r < 4; ++r)
        o[r] = (acc[j][r] - mu) * rstd * gv[r] + btv[r];
      *(f32x4*)(orow + j * 16 + g4) = o;
    }
  }
}

// Pack W [K][N] f32 -> bf16, elem off = p*(N*32) + kc*(N*8) + n*8 (frag-contiguous).
__global__ void prep_pack(const float* __restrict__ W, unsigned short* __restrict__ P,
                          int K, int N) {
  const int t = blockIdx.x * blockDim.x + threadIdx.x;
  if (t >= N * (K >> 3)) return;
  const int n = t % N;
  const int k8 = t / N;
  const int k0 = k8 << 3;
  const int p = k0 >> 5, kc = (k0 >> 3) & 3;
  s16x8 w;
  #pragma unroll
  for (int j = 0; j < 8; ++j) {
    union { float f; unsigned u; } t_; t_.f = W[(size_t)(k0 + j) * N + n];
    w[j] = (short)((t_.u + 0x8000u) >> 16);
  }
  *(s16x8*)(P + (size_t)p * N * 32 + (size_t)kc * N * 8 + (size_t)n * 8) = w;
}

extern "C" void kernel_launch(void* const* d_in, const int* in_sizes, int n_in,
                              void* d_out, int out_size, void* d_ws, size_t ws_size,
                              hipStream_t stream) {
  const float* efeat    = (const float*)d_in[0];
  const float* src_feat = (const float*)d_in[1];
  const float* dst_feat = (const float*)d_in[2];
  const int*   src_idx  = (const int*)d_in[3];
  const int*   dst_idx  = (const int*)d_in[4];
  const float* W1 = (const float*)d_in[5];
  const float* b1 = (const float*)d_in[6];
  const float* W2 = (const float*)d_in[7];
  const float* b2 = (const float*)d_in[8];
  const float* W3 = (const float*)d_in[9];
  const float* b3 = (const float*)d_in[10];
  const float* gamma = (const float*)d_in[11];
  const float* beta  = (const float*)d_in[12];

  unsigned short* P1 = (unsigned short*)d_ws;           // 196608 elems
  unsigned short* P2 = P1 + 196608;                     // 262144
  unsigned short* P3 = P2 + 262144;                     // 65536

  (void)hipFuncSetAttribute((const void*)edge_mlp_fused,
                            hipFuncAttributeMaxDynamicSharedMemorySize, LDS_TOTAL);

  prep_pack<<<(512 * 48 + 255) / 256, 256, 0, stream>>>(W1, P1, CAT_, H_);
  prep_pack<<<(512 * 64 + 255) / 256, 256, 0, stream>>>(W2, P2, H_, H_);
  prep_pack<<<(128 * 64 + 255) / 256, 256, 0, stream>>>(W3, P3, H_, D_);

  edge_mlp_fused<<<NBLK, 1024, LDS_TOTAL, stream>>>(
      efeat, src_feat, dst_feat, src_idx, dst_idx,
      P1, P2, P3, b1, b2, b3, gamma, beta, (float*)d_out);
}

// Round 17
// 524.979 us; speedup vs baseline: 1.0350x; 1.0350x over previous
//
#include <hip/hip_runtime.h>
#include <hip/hip_bf16.h>
#include <cstdint>
#include <cstddef>

typedef __attribute__((ext_vector_type(4))) float f32x4;
typedef __attribute__((ext_vector_type(8))) short s16x8;
typedef __attribute__((ext_vector_type(4))) unsigned int u32x4;

#define E_ 400000
#define D_ 128
#define H_ 512
#define CAT_ 384
#define BM 64
#define NBLK 6250                       // 400000/64 exact, no tail
#define SCRATCH 65536                   // 1KB LN partial-sum scratch after h
#define LDS_TOTAL (65536 + 1024)        // 66560 -> 2 blocks/CU
// cat (64 x 384 bf16) staged INSIDE the h buffer rows (h dead until the
// post-GEMM1 silu stores, which come after a barrier).
// NOTE: no K-loop rotation — co-resident blocks (i, i+256) read IDENTICAL
// W streams in the same order, so the trailing block's W loads hit L1.

__device__ __forceinline__ unsigned cvtpk(float lo, float hi) {
  unsigned r;
  asm("v_cvt_pk_bf16_f32 %0, %1, %2" : "=v"(r) : "v"(lo), "v"(hi));
  return r;
}
__device__ __forceinline__ float silu_f(float x) {
  return x * __builtin_amdgcn_rcpf(1.0f + __expf(-x));
}

// h row stride 1024B would be 32-way bank conflict; XOR spread fixes it.
#define HS(row, byteoff) (smem + (row) * 1024 + ((byteoff) ^ (((row) & 7) << 4)))

// Swapped-operand MFMA: A = W frag (out-cols), B = activation frag (edges).
// D: lane&15 = edge, (lane>>4)*4 + r = out-col.
__global__ __launch_bounds__(512, 4)
void edge_mlp_fused(const float* __restrict__ efeat,
                    const float* __restrict__ src_feat,
                    const float* __restrict__ dst_feat,
                    const int* __restrict__ src_idx,
                    const int* __restrict__ dst_idx,
                    const unsigned short* __restrict__ P1,   // packed: p*16384 + kc*4096 + n*8
                    const unsigned short* __restrict__ P2,
                    const unsigned short* __restrict__ P3,   // p*4096 + kc*1024 + n*8
                    const float* __restrict__ b1,
                    const float* __restrict__ b2,
                    const float* __restrict__ b3,
                    const float* __restrict__ gamma,
                    const float* __restrict__ beta,
                    float* __restrict__ out) {
  extern __shared__ char smem[];
  const int tid = threadIdx.x;
  const int lane = tid & 63;
  const int wave = tid >> 6;            // 0..7
  const int lr = lane & 15;
  const int kc = lane >> 4;             // 0..3
  const int g4 = kc * 4;
  const size_t e0 = (size_t)blockIdx.x * BM;

  // per-wave W fragment base pointers (frag = contiguous 16B)
  const unsigned short* w1base = P1 + (size_t)kc * 4096 + wave * 512 + lr * 8;
  const unsigned short* w2base = P2 + (size_t)kc * 4096 + wave * 512 + lr * 8;

  // gather mapping: 8 threads per edge row, 16 floats each per source
  const int grow = tid >> 3, gq = tid & 7;
  const size_t ee = e0 + grow;

#define LOAD4(dst, base) { const float* s0_ = (base) + gq * 8; \
  dst[0] = *(const f32x4*)s0_;        dst[1] = *(const f32x4*)(s0_ + 4); \
  dst[2] = *(const f32x4*)(s0_ + 64); dst[3] = *(const f32x4*)(s0_ + 68); }

#define STASH(v, scol) { \
  u32x4 r0_, r1_; \
  r0_.x = cvtpk(v[0][0], v[0][1]); r0_.y = cvtpk(v[0][2], v[0][3]); \
  r0_.z = cvtpk(v[1][0], v[1][1]); r0_.w = cvtpk(v[1][2], v[1][3]); \
  r1_.x = cvtpk(v[2][0], v[2][1]); r1_.y = cvtpk(v[2][2], v[2][3]); \
  r1_.z = cvtpk(v[3][0], v[3][1]); r1_.w = cvtpk(v[3][2], v[3][3]); \
  *(u32x4*)HS(grow, ((scol) + gq * 8) * 2) = r0_; \
  *(u32x4*)HS(grow, ((scol) + 64 + gq * 8) * 2) = r1_; }

  // ========== GEMM1 with async gather: efeat FIRST (so its stash waits
  // vmcnt(4), leaving src in flight across the barrier -> tier0 covers it) ==========
  {
    f32x4 acc[4][4];
    #pragma unroll
    for (int eg = 0; eg < 4; ++eg)
      #pragma unroll
      for (int j = 0; j < 4; ++j) acc[eg][j] = (f32x4){0.f, 0.f, 0.f, 0.f};

    const float* psrc = src_feat + (size_t)src_idx[ee] * D_;
    const float* pdst = dst_feat + (size_t)dst_idx[ee] * D_;

    f32x4 gx[4], gs[4];
    LOAD4(gx, efeat + ee * D_);               // oldest 4 loads: efeat
    LOAD4(gs, psrc);                          // src in flight (parked)
    STASH(gx, 0);                             // waits efeat only (vmcnt(4))

    asm volatile("s_waitcnt lgkmcnt(0)" ::: "memory");
    __builtin_amdgcn_s_barrier();
    asm volatile("" ::: "memory");

    auto g1tier = [&](int P0) {
      const unsigned short* wp = w1base + (size_t)P0 * 16384;
      #pragma unroll 1                        // cap w in-flight at 16 regs (spill guard)
      for (int pp = 0; pp < 4; ++pp) {
        s16x8 w[4];
        #pragma unroll
        for (int j = 0; j < 4; ++j)
          w[j] = *(const s16x8*)(wp + j * 128);
        const int p = P0 + pp;
        #pragma unroll
        for (int eg = 0; eg < 4; ++eg) {      // bf loaded per-eg: no reg bump
          const s16x8 bf = *(const s16x8*)HS(eg * 16 + lr, p * 64 + kc * 16);
          #pragma unroll
          for (int j = 0; j < 4; ++j)
            acc[eg][j] = __builtin_amdgcn_mfma_f32_16x16x32_bf16(w[j], bf, acc[eg][j], 0, 0, 0);
        }
        wp += 16384;
      }
    };

    g1tier(0);                                // efeat cols; covers src latency
    STASH(gs, 128);                           // src lands
    LOAD4(gx, pdst);                          // dst in flight
    asm volatile("s_waitcnt lgkmcnt(0)" ::: "memory");
    __builtin_amdgcn_s_barrier();
    asm volatile("" ::: "memory");

    g1tier(4);                                // src cols; covers dst latency
    STASH(gx, 256);                           // dst lands
    asm volatile("s_waitcnt lgkmcnt(0)" ::: "memory");
    __builtin_amdgcn_s_barrier();
    asm volatile("" ::: "memory");

    g1tier(8);                                // dst cols

    __builtin_amdgcn_s_barrier();             // all cat reads done before h1 overwrite
    asm volatile("" ::: "memory");

    #pragma unroll
    for (int j = 0; j < 4; ++j) {
      const int col0 = (wave * 4 + j) * 16 + g4;
      const f32x4 bv = *(const f32x4*)(b1 + col0);
      #pragma unroll
      for (int eg = 0; eg < 4; ++eg) {
        uint2 o_;
        o_.x = cvtpk(silu_f(acc[eg][j][0] + bv[0]), silu_f(acc[eg][j][1] + bv[1]));
        o_.y = cvtpk(silu_f(acc[eg][j][2] + bv[2]), silu_f(acc[eg][j][3] + bv[3]));
        *(uint2*)HS(eg * 16 + lr, col0 * 2) = o_;
      }
    }
  }
  asm volatile("s_waitcnt lgkmcnt(0)" ::: "memory");
  __builtin_amdgcn_s_barrier();               // h1 visible
  asm volatile("" ::: "memory");

  // ========== GEMM2: h1[64x512] @ W2 -> silu -> h2 (barrier-free K-loop) ==========
  {
    f32x4 acc[4][4];
    #pragma unroll
    for (int eg = 0; eg < 4; ++eg)
      #pragma unroll
      for (int j = 0; j < 4; ++j) acc[eg][j] = (f32x4){0.f, 0.f, 0.f, 0.f};

    #pragma unroll 2
    for (int p = 0; p < 16; ++p) {
      s16x8 w[4];
      #pragma unroll
      for (int j = 0; j < 4; ++j)
        w[j] = *(const s16x8*)(w2base + (size_t)p * 16384 + j * 128);
      #pragma unroll
      for (int eg = 0; eg < 4; ++eg) {        // bf per-eg: no reg bump
        const s16x8 bf = *(const s16x8*)HS(eg * 16 + lr, p * 64 + kc * 16);
        #pragma unroll
        for (int j = 0; j < 4; ++j)
          acc[eg][j] = __builtin_amdgcn_mfma_f32_16x16x32_bf16(w[j], bf, acc[eg][j], 0, 0, 0);
      }
    }

    __builtin_amdgcn_s_barrier();             // all h1 reads done before h2 overwrite
    asm volatile("" ::: "memory");

    #pragma unroll
    for (int j = 0; j < 4; ++j) {
      const int col0 = (wave * 4 + j) * 16 + g4;
      const f32x4 bv = *(const f32x4*)(b2 + col0);
      #pragma unroll
      for (int eg = 0; eg < 4; ++eg) {
        uint2 o_;
        o_.x = cvtpk(silu_f(acc[eg][j][0] + bv[0]), silu_f(acc[eg][j][1] + bv[1]));
        o_.y = cvtpk(silu_f(acc[eg][j][2] + bv[2]), silu_f(acc[eg][j][3] + bv[3]));
        *(uint2*)HS(eg * 16 + lr, col0 * 2) = o_;
      }
    }
  }
  asm volatile("s_waitcnt lgkmcnt(0)" ::: "memory");
  __builtin_amdgcn_s_barrier();               // h2 visible
  asm volatile("" ::: "memory");

  // ===== GEMM3: 8 waves, wave = (edge-group, col-half); LN via LDS partials =====
  {
    const int eg3 = wave >> 1;                // 0..3 : 16-edge group
    const int half = wave & 1;                // 0..1 : 64-col half
    const int edge = eg3 * 16 + lr;

    f32x4 acc[4];
    #pragma unroll
    for (int j = 0; j < 4; ++j) acc[j] = (f32x4){0.f, 0.f, 0.f, 0.f};

    const unsigned short* w3b = P3 + (size_t)kc * 1024 + half * 512 + lr * 8;

    #pragma unroll 2
    for (int p = 0; p < 16; ++p) {
      s16x8 w[4];
      #pragma unroll
      for (int j = 0; j < 4; ++j)
        w[j] = *(const s16x8*)(w3b + (size_t)p * 4096 + j * 128);
      const s16x8 bf = *(const s16x8*)HS(edge, p * 64 + kc * 16);
      #pragma unroll
      for (int j = 0; j < 4; ++j)
        acc[j] = __builtin_amdgcn_mfma_f32_16x16x32_bf16(w[j], bf, acc[j], 0, 0, 0);
    }

    // bias + per-half partial sums (cols half*64 .. half*64+63)
    float sum = 0.f, ss = 0.f;
    #pragma unroll
    for (int j = 0; j < 4; ++j) {
      const f32x4 bv = *(const f32x4*)(b3 + half * 64 + j * 16 + g4);
      #pragma unroll
      for (int r = 0; r < 4; ++r) {
        acc[j][r] += bv[r];
        sum += acc[j][r];
        ss += acc[j][r] * acc[j][r];
      }
    }
    sum += __shfl_xor(sum, 16, 64); ss += __shfl_xor(ss, 16, 64);
    sum += __shfl_xor(sum, 32, 64); ss += __shfl_xor(ss, 32, 64);

    if (lane < 16) {
      float2 pw; pw.x = sum; pw.y = ss;
      *(float2*)(smem + SCRATCH + edge * 16 + half * 8) = pw;
    }
    asm volatile("s_waitcnt lgkmcnt(0)" ::: "memory");
    __builtin_amdgcn_s_barrier();
    asm volatile("" ::: "memory");

    const f32x4 pt = *(const f32x4*)(smem + SCRATCH + edge * 16);
    const float sumT = pt[0] + pt[2];
    const float ssT  = pt[1] + pt[3];
    const float mu = sumT * (1.0f / 128.0f);
    const float var = ssT * (1.0f / 128.0f) - mu * mu;
    const float rstd = rsqrtf(var + 1e-5f);

    float* orow = out + (e0 + edge) * D_ + half * 64;
    #pragma unroll
    for (int j = 0; j < 4; ++j) {
      const f32x4 gv  = *(const f32x4*)(gamma + half * 64 + j * 16 + g4);
      const f32x4 btv = *(const f32x4*)(beta  + half * 64 + j * 16 + g4);
      f32x4 o;
      #pragma unroll
      for (int r = 0; r < 4; ++r)
        o[r] = (acc[j][r] - mu) * rstd * gv[r] + btv[r];
      *(f32x4*)(orow + j * 16 + g4) = o;
    }
  }
#undef LOAD4
#undef STASH
}

// Pack W [K][N] f32 -> bf16, elem off = p*(N*32) + kc*(N*8) + n*8 (frag-contiguous).
__global__ void prep_pack(const float* __restrict__ W, unsigned short* __restrict__ P,
                          int K, int N) {
  const int t = blockIdx.x * blockDim.x + threadIdx.x;
  if (t >= N * (K >> 3)) return;
  const int n = t % N;
  const int k8 = t / N;
  const int k0 = k8 << 3;
  const int p = k0 >> 5, kc = (k0 >> 3) & 3;
  s16x8 w;
  #pragma unroll
  for (int j = 0; j < 8; ++j) {
    union { float f; unsigned u; } t_; t_.f = W[(size_t)(k0 + j) * N + n];
    w[j] = (short)((t_.u + 0x8000u) >> 16);
  }
  *(s16x8*)(P + (size_t)p * N * 32 + (size_t)kc * N * 8 + (size_t)n * 8) = w;
}

extern "C" void kernel_launch(void* const* d_in, const int* in_sizes, int n_in,
                              void* d_out, int out_size, void* d_ws, size_t ws_size,
                              hipStream_t stream) {
  const float* efeat    = (const float*)d_in[0];
  const float* src_feat = (const float*)d_in[1];
  const float* dst_feat = (const float*)d_in[2];
  const int*   src_idx  = (const int*)d_in[3];
  const int*   dst_idx  = (const int*)d_in[4];
  const float* W1 = (const float*)d_in[5];
  const float* b1 = (const float*)d_in[6];
  const float* W2 = (const float*)d_in[7];
  const float* b2 = (const float*)d_in[8];
  const float* W3 = (const float*)d_in[9];
  const float* b3 = (const float*)d_in[10];
  const float* gamma = (const float*)d_in[11];
  const float* beta  = (const float*)d_in[12];

  unsigned short* P1 = (unsigned short*)d_ws;           // 196608 elems
  unsigned short* P2 = P1 + 196608;                     // 262144
  unsigned short* P3 = P2 + 262144;                     // 65536

  (void)hipFuncSetAttribute((const void*)edge_mlp_fused,
                            hipFuncAttributeMaxDynamicSharedMemorySize, LDS_TOTAL);

  prep_pack<<<(512 * 48 + 255) / 256, 256, 0, stream>>>(W1, P1, CAT_, H_);
  prep_pack<<<(512 * 64 + 255) / 256, 256, 0, stream>>>(W2, P2, H_, H_);
  prep_pack<<<(128 * 64 + 255) / 256, 256, 0, stream>>>(W3, P3, H_, D_);

  edge_mlp_fused<<<NBLK, 512, LDS_TOTAL, stream>>>(
      efeat, src_feat, dst_feat, src_idx, dst_idx,
      P1, P2, P3, b1, b2, b3, gamma, beta, (float*)d_out);
}